// Round 9
// baseline (108.916 us; speedup 1.0000x reference)
//
#include <hip/hip_runtime.h>
#include <stdint.h>

// ---------- types ----------
typedef __attribute__((ext_vector_type(8))) __bf16 fragAB;   // 8 bf16 = 4 VGPR
typedef __attribute__((ext_vector_type(4))) float f32x4;
typedef __attribute__((ext_vector_type(16))) float f32x16;
typedef __attribute__((ext_vector_type(4))) unsigned int u32x4;

__device__ __forceinline__ unsigned short f2bf(float f) {
    union { float f; unsigned int u; } v; v.f = f;
    unsigned int u = v.u + 0x7fffu + ((v.u >> 16) & 1u);   // RNE
    return (unsigned short)(u >> 16);
}

__device__ __forceinline__ f32x4 MFMA16(fragAB a, fragAB b, f32x4 c) {
    return __builtin_amdgcn_mfma_f32_16x16x32_bf16(a, b, c, 0, 0, 0);
}
__device__ __forceinline__ f32x16 MFMA32(fragAB a, fragAB b, f32x16 c) {
    return __builtin_amdgcn_mfma_f32_32x32x16_bf16(a, b, c, 0, 0, 0);
}

// async global->LDS, 16B per lane; LDS dest = wave-uniform base + lane*16
__device__ __forceinline__ void gl16(const void* g, void* l) {
    __builtin_amdgcn_global_load_lds((const __attribute__((address_space(1))) void*)g,
                                     (__attribute__((address_space(3))) void*)l, 16, 0, 0);
}

__device__ __forceinline__ float fsin_rev(float rev) {   // sin(2*pi*rev)
    float r; asm("v_sin_f32 %0, %1" : "=v"(r) : "v"(rev)); return r;
}
__device__ __forceinline__ unsigned int cvtpk(float lo, float hi) {  // 2xbf16 RNE
    unsigned int r; asm("v_cvt_pk_bf16_f32 %0, %1, %2" : "=v"(r) : "v"(lo), "v"(hi)); return r;
}
__device__ __forceinline__ void swap32(unsigned int& a, unsigned int& b) {
    // exchanges a's lanes 32-63 with b's lanes 0-31
    asm volatile("v_permlane32_swap_b32 %0, %1" : "+v"(a), "+v"(b));
}

#define SIN_SC 0.5968310366f   // 3.75 / (2*pi)

// ---------- fused fp32 -> bf16 convert (x + 4 weights in one launch) ----------
__global__ __launch_bounds__(256) void cvt_all(
    const float* __restrict__ x,  const float* __restrict__ wq, const float* __restrict__ wk,
    const float* __restrict__ wv, const float* __restrict__ wo,
    unsigned short* __restrict__ xb,  unsigned short* __restrict__ wqb, unsigned short* __restrict__ wkb,
    unsigned short* __restrict__ wvb, unsigned short* __restrict__ wob)
{
    const int bid = blockIdx.x;
    const float* s; unsigned short* d; int off;
    if (bid < 4096)      { s = x;  d = xb;  off = bid; }
    else if (bid < 5120) { s = wq; d = wqb; off = bid - 4096; }
    else if (bid < 6144) { s = wk; d = wkb; off = bid - 5120; }
    else if (bid < 7168) { s = wv; d = wvb; off = bid - 6144; }
    else                 { s = wo; d = wob; off = bid - 7168; }
    const int i = (off * 256 + threadIdx.x) * 4;
    float4 f = *(const float4*)(s + i);
    ushort4 o;
    o.x = f2bf(f.x); o.y = f2bf(f.y); o.z = f2bf(f.z); o.w = f2bf(f.w);
    *(ushort4*)(d + i) = o;
}

// ---------- GEMM (m97 structure, 128x128): Q/K/V projections ----------
// z=0: Q row-major bf16 (unscaled). z=1: Kshuf. z=2: Vshuf (frag order).
__global__ __launch_bounds__(256, 2)
void gemm_k(const unsigned short* __restrict__ A,
            const unsigned short* __restrict__ W0, const unsigned short* __restrict__ W1,
            const unsigned short* __restrict__ W2,
            const float* __restrict__ b0, const float* __restrict__ b1, const float* __restrict__ b2,
            void* o0, void* o1, void* o2)
{
    __shared__ unsigned short As[8192];   // [128][64] linear, 16KB
    __shared__ unsigned short Ws[8192];

    const int z = blockIdx.z;
    const unsigned short* W = z == 0 ? W0 : (z == 1 ? W1 : W2);
    const float* bias        = z == 0 ? b0 : (z == 1 ? b1 : b2);
    void* out                = z == 0 ? o0 : (z == 1 ? o1 : o2);

    const int t = threadIdx.x;
    const int lane = t & 63;
    const int g = lane >> 4;
    const int c = lane & 15;
    const int w = t >> 6;
    const int wm = (w >> 1) * 64;
    const int wn = (w & 1) * 64;
    const int m0 = blockIdx.y * 128;
    const int n0 = blockIdx.x * 128;

    const int srow = lane >> 3;
    const int scol = (lane & 7) * 8;

    const f32x4 zz = {0.f, 0.f, 0.f, 0.f};
    f32x4 acc[4][4];
#pragma unroll
    for (int mi = 0; mi < 4; ++mi)
#pragma unroll
        for (int ni = 0; ni < 4; ++ni) acc[mi][ni] = zz;

    for (int kt = 0; kt < 16; ++kt) {
        const int k0 = kt * 64;
#pragma unroll
        for (int r = 0; r < 4; ++r) {
            gl16(A + (size_t)(m0 + 32 * w + 8 * r + srow) * 1024 + k0 + scol,
                 (unsigned short*)As + (w * 4 + r) * 512);
            gl16(W + (size_t)(n0 + 32 * w + 8 * r + srow) * 1024 + k0 + scol,
                 (unsigned short*)Ws + (w * 4 + r) * 512);
        }
        __syncthreads();
#pragma unroll
        for (int kk = 0; kk < 2; ++kk) {
            fragAB af[4], bfr[4];
#pragma unroll
            for (int mi = 0; mi < 4; ++mi)
                af[mi] = *(const fragAB*)((char*)As + (wm + mi * 16 + c) * 128 + kk * 64 + g * 16);
#pragma unroll
            for (int ni = 0; ni < 4; ++ni)
                bfr[ni] = *(const fragAB*)((char*)Ws + (wn + ni * 16 + c) * 128 + kk * 64 + g * 16);
#pragma unroll
            for (int mi = 0; mi < 4; ++mi)
#pragma unroll
                for (int ni = 0; ni < 4; ++ni)
                    acc[mi][ni] = MFMA16(af[mi], bfr[ni], acc[mi][ni]);
        }
        __syncthreads();
    }

    float bv[4];
#pragma unroll
    for (int ni = 0; ni < 4; ++ni) bv[ni] = bias[n0 + wn + ni * 16 + c];

    if (z == 0) {                                // Q: row-major bf16 (unscaled)
        unsigned short* C = (unsigned short*)out;
#pragma unroll
        for (int mi = 0; mi < 4; ++mi)
#pragma unroll
            for (int ni = 0; ni < 4; ++ni)
#pragma unroll
                for (int j = 0; j < 4; ++j) {
                    const int grow = m0 + wm + mi * 16 + g * 4 + j;
                    const int gcol = n0 + wn + ni * 16 + c;
                    C[(size_t)grow * 1024 + gcol] = f2bf(acc[mi][ni][j] + bv[ni]);
                }
    } else if (z == 1) {                         // Kshuf scatter (2B stores)
        unsigned short* Ksh = (unsigned short*)out;
#pragma unroll
        for (int mi = 0; mi < 4; ++mi) {
            const int s0 = m0 + wm + mi * 16 + g * 4;
            const int b_ = s0 >> 11, sr = s0 & 2047;
            const int kb = sr >> 6, kbl = (sr >> 5) & 1;
            const int l31b = (mi & 1) * 16 + g * 4;
#pragma unroll
            for (int ni = 0; ni < 4; ++ni) {
                const int n = n0 + wn + ni * 16 + c;
                const int h_ = n >> 6, d = n & 63;
                const int ds = d >> 4, e = d & 7, lhalf = (d >> 3) & 1;
                const size_t base =
                    ((((size_t)(b_ * 16 + h_) * 32 + kb) * 2 + kbl) * 4 + ds) * 512
                    + lhalf * 256 + (size_t)l31b * 8 + e;
#pragma unroll
                for (int j = 0; j < 4; ++j)
                    Ksh[base + j * 8] = f2bf(acc[mi][ni][j] + bv[ni]);
            }
        }
    } else {                                     // Vshuf scatter (8B stores)
        unsigned short* Vsh = (unsigned short*)out;
#pragma unroll
        for (int mi = 0; mi < 4; ++mi) {
            const int s0 = m0 + wm + mi * 16 + g * 4;
            const int b_ = s0 >> 11, sr = s0 & 2047;
            const int kb = sr >> 6;
            const int kslice = mi;               // (mi*16+g*4)>>4
            const int khalf = (g >> 1) & 1;
            const int e0 = (g & 1) * 4;
#pragma unroll
            for (int ni = 0; ni < 4; ++ni) {
                const int n = n0 + wn + ni * 16 + c;
                const int h_ = n >> 6;
                const int nei = ni >> 1;
                const int l31 = (ni & 1) * 16 + c;
                const size_t base =
                    ((((size_t)(b_ * 16 + h_) * 32 + kb) * 4 + kslice) * 2 + nei) * 512
                    + (size_t)(khalf * 32 + l31) * 8 + e0;
                ushort4 pk;
                pk.x = f2bf(acc[mi][ni][0] + bv[ni]);
                pk.y = f2bf(acc[mi][ni][1] + bv[ni]);
                pk.z = f2bf(acc[mi][ni][2] + bv[ni]);
                pk.w = f2bf(acc[mi][ni][3] + bv[ni]);
                *(ushort4*)(Vsh + base) = pk;
            }
        }
    }
}

// ---------- GEMM 64x128 tile, fp32 out: final projection ----------
__global__ __launch_bounds__(256, 4)
void gemm64(const unsigned short* __restrict__ A,
            const unsigned short* __restrict__ W,
            const float* __restrict__ bias, float* __restrict__ out)
{
    __shared__ unsigned short As[4096];   // [64][64]  8KB
    __shared__ unsigned short Ws[8192];   // [128][64] 16KB

    const int t = threadIdx.x;
    const int lane = t & 63;
    const int g = lane >> 4;
    const int c = lane & 15;
    const int w = t >> 6;
    const int wm = (w >> 1) * 32;
    const int wn = (w & 1) * 64;
    const int m0 = blockIdx.y * 64;
    const int n0 = blockIdx.x * 128;

    const int srow = lane >> 3;
    const int scol = (lane & 7) * 8;

    const f32x4 zz = {0.f, 0.f, 0.f, 0.f};
    f32x4 acc[2][4];
#pragma unroll
    for (int mi = 0; mi < 2; ++mi)
#pragma unroll
        for (int ni = 0; ni < 4; ++ni) acc[mi][ni] = zz;

    for (int kt = 0; kt < 16; ++kt) {
        const int k0 = kt * 64;
        gl16(A + (size_t)(m0 + 16 * w + srow) * 1024 + k0 + scol,
             (unsigned short*)As + (2 * w) * 512);
        gl16(A + (size_t)(m0 + 16 * w + 8 + srow) * 1024 + k0 + scol,
             (unsigned short*)As + (2 * w + 1) * 512);
#pragma unroll
        for (int r = 0; r < 4; ++r)
            gl16(W + (size_t)(n0 + 32 * w + 8 * r + srow) * 1024 + k0 + scol,
                 (unsigned short*)Ws + (w * 4 + r) * 512);
        __syncthreads();
#pragma unroll
        for (int kk = 0; kk < 2; ++kk) {
            fragAB af[2], bfr[4];
#pragma unroll
            for (int mi = 0; mi < 2; ++mi)
                af[mi] = *(const fragAB*)((char*)As + (wm + mi * 16 + c) * 128 + kk * 64 + g * 16);
#pragma unroll
            for (int ni = 0; ni < 4; ++ni)
                bfr[ni] = *(const fragAB*)((char*)Ws + (wn + ni * 16 + c) * 128 + kk * 64 + g * 16);
#pragma unroll
            for (int mi = 0; mi < 2; ++mi)
#pragma unroll
                for (int ni = 0; ni < 4; ++ni)
                    acc[mi][ni] = MFMA16(af[mi], bfr[ni], acc[mi][ni]);
        }
        __syncthreads();
    }

#pragma unroll
    for (int ni = 0; ni < 4; ++ni) {
        const float bv = bias[n0 + wn + ni * 16 + c];
#pragma unroll
        for (int mi = 0; mi < 2; ++mi)
#pragma unroll
            for (int j = 0; j < 4; ++j) {
                const int grow = m0 + wm + mi * 16 + g * 4 + j;
                const int gcol = n0 + wn + ni * 16 + c;
                out[(size_t)grow * 1024 + gcol] = acc[mi][ni][j] + bv;
            }
    }
}

// ---------- fused sine attention v5: K in LDS, V direct global->reg ----------
// 8 waves (4 q-quarters x 2 k-halves), QBLK=128, KVBLK=64, grid 512 XCD-chunked.
// Per iter: V(kb)->regs (4x coalesced 1KB dwordx4, covered by QK+sin latency);
// K(kb+1) gl16 into LDS dbuf; QK from LDS kf; sin->permlane P; PV from reg vf.
// LDS traffic halved vs v4b (K only). One barrier/iter.
__global__ __launch_bounds__(512, 4)
void attn_kernel(const unsigned short* __restrict__ Qg,
                 const unsigned short* __restrict__ Ksh,
                 const unsigned short* __restrict__ Vsh,
                 unsigned short* __restrict__ AO)
{
    __shared__ char smem[32768];
    unsigned short* const KldsU = (unsigned short*)smem;   // 2 bufs x 8KB (K only)
    float* const red = (float*)smem;                       // 32KB reduce (aliased)

    const int t = threadIdx.x;
    const int lane = t & 63;
    const int l31 = lane & 31;
    const int lh = lane >> 5;
    const int w = t >> 6;
    const int qh = w >> 1;     // q-quarter owned (32 rows)
    const int kbl = w & 1;     // k-half owned

    // XCD-chunked bijective swizzle (512 blocks, 64 per XCD)
    const int bid = blockIdx.x;
    const int lb = (bid & 7) * 64 + (bid >> 3);
    const int qb = lb & 15;
    const int h = (lb >> 4) & 15;
    const int b = lb >> 8;
    const int qbase = qb * 128;

    const unsigned short* Kc = Ksh + (size_t)(b * 16 + h) * 131072;
    const unsigned short* Vc = Vsh + (size_t)(b * 16 + h) * 131072;

    // Q fragments (loop-invariant): lane holds Q[qbase+qh*32+l31][ds*16+lh*8..+8]
    fragAB qf[4];
#pragma unroll
    for (int ds = 0; ds < 4; ++ds)
        qf[ds] = *(const fragAB*)(Qg
            + (size_t)(b * 2048 + qbase + qh * 32 + l31) * 1024
            + h * 64 + ds * 16 + lh * 8);

    f32x16 o[2];
#pragma unroll
    for (int ni = 0; ni < 2; ++ni)
#pragma unroll
        for (int r = 0; r < 16; ++r) o[ni][r] = 0.f;

    // per-wave V fragment base (contiguous 1KB blocks, coalesced)
    const unsigned short* Vw = Vc + (size_t)(kbl * 4) * 512 + lane * 8;

    // prologue: stage K(0) into buf 0 (each wave: 1 block of 1KB)
    gl16(Kc + w * 512 + lane * 8, KldsU + w * 512);
    __syncthreads();

    for (int kb = 0; kb < 32; ++kb) {
        const int buf = kb & 1;

        // V(kb) -> regs FIRST (so vf's waitcnt doesn't stall on the K gl16 below)
        fragAB vf[2][2];
#pragma unroll
        for (int ks = 0; ks < 2; ++ks)
#pragma unroll
            for (int ni = 0; ni < 2; ++ni)
                vf[ks][ni] = *(const fragAB*)(Vw + (size_t)kb * 4096 + (ks * 2 + ni) * 512);

        if (kb < 31) {   // stage K(kb+1) into buf^1 (drained by bottom syncthreads)
            gl16(Kc + (size_t)(kb + 1) * 4096 + w * 512 + lane * 8,
                 KldsU + (buf ^ 1) * 4096 + w * 512);
        }

        // conflict-free K frag reads (lane*16B each)
        fragAB kf[4];
#pragma unroll
        for (int ds = 0; ds < 4; ++ds)
            kf[ds] = *(const fragAB*)(KldsU + buf * 4096 + (kbl * 4 + ds) * 512 + lane * 8);

        // QK: St = K(own 32k) . Q(own 32q)^T over d=64
        f32x16 st;
#pragma unroll
        for (int r = 0; r < 16; ++r) st[r] = 0.f;
        __builtin_amdgcn_s_setprio(1);
#pragma unroll
        for (int ds = 0; ds < 4; ++ds)
            st = MFMA32(kf[ds], qf[ds], st);
        __builtin_amdgcn_s_setprio(0);

        // sin(SIN_SC * st) -> bf16 pairs -> permlane32_swap -> PV A-frags
        unsigned int u[8];
#pragma unroll
        for (int i = 0; i < 8; ++i)
            u[i] = cvtpk(fsin_rev(st[2 * i] * SIN_SC), fsin_rev(st[2 * i + 1] * SIN_SC));
        swap32(u[0], u[2]); swap32(u[1], u[3]);
        swap32(u[4], u[6]); swap32(u[5], u[7]);
        union { u32x4 u; fragAB f; } pa0, pa1;
        pa0.u = (u32x4){u[0], u[1], u[2], u[3]};
        pa1.u = (u32x4){u[4], u[5], u[6], u[7]};

        __builtin_amdgcn_s_setprio(1);
#pragma unroll
        for (int ni = 0; ni < 2; ++ni) {
            o[ni] = MFMA32(pa0.f, vf[0][ni], o[ni]);
            o[ni] = MFMA32(pa1.f, vf[1][ni], o[ni]);
        }
        __builtin_amdgcn_s_setprio(0);

        __syncthreads();   // K(kb+1) staged; buf readers done
    }

    // cross-k-half reduce: kbl=1 waves write partial O, kbl=0 waves add + store
    if (kbl) {
#pragma unroll
        for (int ni = 0; ni < 2; ++ni)
#pragma unroll
            for (int r = 0; r < 16; ++r)
                red[((qh * 2 + ni) * 16 + r) * 64 + lane] = o[ni][r];
    }
    __syncthreads();
    if (!kbl) {
#pragma unroll
        for (int ni = 0; ni < 2; ++ni)
#pragma unroll
            for (int r = 0; r < 16; ++r) {
                const float v = o[ni][r]
                    + red[((qh * 2 + ni) * 16 + r) * 64 + lane];
                const int q = qbase + qh * 32 + (r & 3) + 8 * (r >> 2) + 4 * lh;
                AO[(size_t)(b * 2048 + q) * 1024 + h * 64 + ni * 32 + l31] = f2bf(v);
            }
    }
}

// ---------- launcher ----------
extern "C" void kernel_launch(void* const* d_in, const int* in_sizes, int n_in,
                              void* d_out, int out_size, void* d_ws, size_t ws_size,
                              hipStream_t stream) {
    (void)in_sizes; (void)n_in; (void)out_size; (void)ws_size;
    const float* x  = (const float*)d_in[0];
    const float* Wq = (const float*)d_in[1];
    const float* bq = (const float*)d_in[2];
    const float* Wk = (const float*)d_in[3];
    const float* bk = (const float*)d_in[4];
    const float* Wv = (const float*)d_in[5];
    const float* bv = (const float*)d_in[6];
    const float* Wo = (const float*)d_in[7];
    const float* bo = (const float*)d_in[8];

    char* ws = (char*)d_ws;
    unsigned short* xb    = (unsigned short*)(ws);                    // 8MB
    unsigned short* Wqb   = (unsigned short*)(ws + (8u  << 20));      // 2MB each
    unsigned short* Wkb   = (unsigned short*)(ws + (10u << 20));
    unsigned short* Wvb   = (unsigned short*)(ws + (12u << 20));
    unsigned short* Wob   = (unsigned short*)(ws + (14u << 20));
    unsigned short* Qb    = (unsigned short*)(ws + (16u << 20));      // 8MB row-major
    unsigned short* Kshuf = (unsigned short*)(ws + (24u << 20));      // 8MB frag-order
    unsigned short* Vshuf = (unsigned short*)(ws + (32u << 20));      // 8MB frag-order
    unsigned short* AO    = (unsigned short*)(ws + (40u << 20));      // 8MB row-major

    cvt_all<<<8192, 256, 0, stream>>>(x, Wq, Wk, Wv, Wo, xb, Wqb, Wkb, Wvb, Wob);

    gemm_k<<<dim3(8, 32, 3), 256, 0, stream>>>(xb, Wqb, Wkb, Wvb, bq, bk, bv,
                                               Qb, Kshuf, Vshuf);

    attn_kernel<<<512, 512, 0, stream>>>(Qb, Kshuf, Vshuf, AO);

    gemm64<<<dim3(8, 64), 256, 0, stream>>>(AO, Wob, bo, (float*)d_out);
}

// Round 10
// 104.119 us; speedup vs baseline: 1.0461x; 1.0461x over previous
//
#include <hip/hip_runtime.h>
#include <stdint.h>

// ---------- types ----------
typedef __attribute__((ext_vector_type(8))) __bf16 fragAB;   // 8 bf16 = 4 VGPR
typedef __attribute__((ext_vector_type(4))) float f32x4;
typedef __attribute__((ext_vector_type(16))) float f32x16;
typedef __attribute__((ext_vector_type(4))) unsigned int u32x4;

__device__ __forceinline__ unsigned short f2bf(float f) {
    union { float f; unsigned int u; } v; v.f = f;
    unsigned int u = v.u + 0x7fffu + ((v.u >> 16) & 1u);   // RNE
    return (unsigned short)(u >> 16);
}

__device__ __forceinline__ f32x4 MFMA16(fragAB a, fragAB b, f32x4 c) {
    return __builtin_amdgcn_mfma_f32_16x16x32_bf16(a, b, c, 0, 0, 0);
}
__device__ __forceinline__ f32x16 MFMA32(fragAB a, fragAB b, f32x16 c) {
    return __builtin_amdgcn_mfma_f32_32x32x16_bf16(a, b, c, 0, 0, 0);
}

// async global->LDS, 16B per lane; LDS dest = wave-uniform base + lane*16
__device__ __forceinline__ void gl16(const void* g, void* l) {
    __builtin_amdgcn_global_load_lds((const __attribute__((address_space(1))) void*)g,
                                     (__attribute__((address_space(3))) void*)l, 16, 0, 0);
}

__device__ __forceinline__ float fsin_rev(float rev) {   // sin(2*pi*rev)
    float r; asm("v_sin_f32 %0, %1" : "=v"(r) : "v"(rev)); return r;
}
__device__ __forceinline__ unsigned int cvtpk(float lo, float hi) {  // 2xbf16 RNE
    unsigned int r; asm("v_cvt_pk_bf16_f32 %0, %1, %2" : "=v"(r) : "v"(lo), "v"(hi)); return r;
}
__device__ __forceinline__ void swap32(unsigned int& a, unsigned int& b) {
    // exchanges a's lanes 32-63 with b's lanes 0-31
    asm volatile("v_permlane32_swap_b32 %0, %1" : "+v"(a), "+v"(b));
}

#define SIN_SC 0.5968310366f   // 3.75 / (2*pi)

// ---------- fused fp32 -> bf16 convert (x + 4 weights in one launch) ----------
__global__ __launch_bounds__(256) void cvt_all(
    const float* __restrict__ x,  const float* __restrict__ wq, const float* __restrict__ wk,
    const float* __restrict__ wv, const float* __restrict__ wo,
    unsigned short* __restrict__ xb,  unsigned short* __restrict__ wqb, unsigned short* __restrict__ wkb,
    unsigned short* __restrict__ wvb, unsigned short* __restrict__ wob)
{
    const int bid = blockIdx.x;
    const float* s; unsigned short* d; int off;
    if (bid < 4096)      { s = x;  d = xb;  off = bid; }
    else if (bid < 5120) { s = wq; d = wqb; off = bid - 4096; }
    else if (bid < 6144) { s = wk; d = wkb; off = bid - 5120; }
    else if (bid < 7168) { s = wv; d = wvb; off = bid - 6144; }
    else                 { s = wo; d = wob; off = bid - 7168; }
    const int i = (off * 256 + threadIdx.x) * 4;
    float4 f = *(const float4*)(s + i);
    ushort4 o;
    o.x = f2bf(f.x); o.y = f2bf(f.y); o.z = f2bf(f.z); o.w = f2bf(f.w);
    *(ushort4*)(d + i) = o;
}

// ---------- GEMM (m97 structure, 128x128): Q/K/V projections ----------
// z=0: Q row-major bf16 (unscaled). z=1: Kshuf. z=2: Vshuf (frag order).
__global__ __launch_bounds__(256, 2)
void gemm_k(const unsigned short* __restrict__ A,
            const unsigned short* __restrict__ W0, const unsigned short* __restrict__ W1,
            const unsigned short* __restrict__ W2,
            const float* __restrict__ b0, const float* __restrict__ b1, const float* __restrict__ b2,
            void* o0, void* o1, void* o2)
{
    __shared__ unsigned short As[8192];   // [128][64] linear, 16KB
    __shared__ unsigned short Ws[8192];

    const int z = blockIdx.z;
    const unsigned short* W = z == 0 ? W0 : (z == 1 ? W1 : W2);
    const float* bias        = z == 0 ? b0 : (z == 1 ? b1 : b2);
    void* out                = z == 0 ? o0 : (z == 1 ? o1 : o2);

    const int t = threadIdx.x;
    const int lane = t & 63;
    const int g = lane >> 4;
    const int c = lane & 15;
    const int w = t >> 6;
    const int wm = (w >> 1) * 64;
    const int wn = (w & 1) * 64;
    const int m0 = blockIdx.y * 128;
    const int n0 = blockIdx.x * 128;

    const int srow = lane >> 3;
    const int scol = (lane & 7) * 8;

    const f32x4 zz = {0.f, 0.f, 0.f, 0.f};
    f32x4 acc[4][4];
#pragma unroll
    for (int mi = 0; mi < 4; ++mi)
#pragma unroll
        for (int ni = 0; ni < 4; ++ni) acc[mi][ni] = zz;

    for (int kt = 0; kt < 16; ++kt) {
        const int k0 = kt * 64;
#pragma unroll
        for (int r = 0; r < 4; ++r) {
            gl16(A + (size_t)(m0 + 32 * w + 8 * r + srow) * 1024 + k0 + scol,
                 (unsigned short*)As + (w * 4 + r) * 512);
            gl16(W + (size_t)(n0 + 32 * w + 8 * r + srow) * 1024 + k0 + scol,
                 (unsigned short*)Ws + (w * 4 + r) * 512);
        }
        __syncthreads();
#pragma unroll
        for (int kk = 0; kk < 2; ++kk) {
            fragAB af[4], bfr[4];
#pragma unroll
            for (int mi = 0; mi < 4; ++mi)
                af[mi] = *(const fragAB*)((char*)As + (wm + mi * 16 + c) * 128 + kk * 64 + g * 16);
#pragma unroll
            for (int ni = 0; ni < 4; ++ni)
                bfr[ni] = *(const fragAB*)((char*)Ws + (wn + ni * 16 + c) * 128 + kk * 64 + g * 16);
#pragma unroll
            for (int mi = 0; mi < 4; ++mi)
#pragma unroll
                for (int ni = 0; ni < 4; ++ni)
                    acc[mi][ni] = MFMA16(af[mi], bfr[ni], acc[mi][ni]);
        }
        __syncthreads();
    }

    float bv[4];
#pragma unroll
    for (int ni = 0; ni < 4; ++ni) bv[ni] = bias[n0 + wn + ni * 16 + c];

    if (z == 0) {                                // Q: row-major bf16 (unscaled)
        unsigned short* C = (unsigned short*)out;
#pragma unroll
        for (int mi = 0; mi < 4; ++mi)
#pragma unroll
            for (int ni = 0; ni < 4; ++ni)
#pragma unroll
                for (int j = 0; j < 4; ++j) {
                    const int grow = m0 + wm + mi * 16 + g * 4 + j;
                    const int gcol = n0 + wn + ni * 16 + c;
                    C[(size_t)grow * 1024 + gcol] = f2bf(acc[mi][ni][j] + bv[ni]);
                }
    } else if (z == 1) {                         // Kshuf scatter (2B stores)
        unsigned short* Ksh = (unsigned short*)out;
#pragma unroll
        for (int mi = 0; mi < 4; ++mi) {
            const int s0 = m0 + wm + mi * 16 + g * 4;
            const int b_ = s0 >> 11, sr = s0 & 2047;
            const int kb = sr >> 6, kbl = (sr >> 5) & 1;
            const int l31b = (mi & 1) * 16 + g * 4;
#pragma unroll
            for (int ni = 0; ni < 4; ++ni) {
                const int n = n0 + wn + ni * 16 + c;
                const int h_ = n >> 6, d = n & 63;
                const int ds = d >> 4, e = d & 7, lhalf = (d >> 3) & 1;
                const size_t base =
                    ((((size_t)(b_ * 16 + h_) * 32 + kb) * 2 + kbl) * 4 + ds) * 512
                    + lhalf * 256 + (size_t)l31b * 8 + e;
#pragma unroll
                for (int j = 0; j < 4; ++j)
                    Ksh[base + j * 8] = f2bf(acc[mi][ni][j] + bv[ni]);
            }
        }
    } else {                                     // Vshuf scatter (8B stores)
        unsigned short* Vsh = (unsigned short*)out;
#pragma unroll
        for (int mi = 0; mi < 4; ++mi) {
            const int s0 = m0 + wm + mi * 16 + g * 4;
            const int b_ = s0 >> 11, sr = s0 & 2047;
            const int kb = sr >> 6;
            const int kslice = mi;               // (mi*16+g*4)>>4
            const int khalf = (g >> 1) & 1;
            const int e0 = (g & 1) * 4;
#pragma unroll
            for (int ni = 0; ni < 4; ++ni) {
                const int n = n0 + wn + ni * 16 + c;
                const int h_ = n >> 6;
                const int nei = ni >> 1;
                const int l31 = (ni & 1) * 16 + c;
                const size_t base =
                    ((((size_t)(b_ * 16 + h_) * 32 + kb) * 4 + kslice) * 2 + nei) * 512
                    + (size_t)(khalf * 32 + l31) * 8 + e0;
                ushort4 pk;
                pk.x = f2bf(acc[mi][ni][0] + bv[ni]);
                pk.y = f2bf(acc[mi][ni][1] + bv[ni]);
                pk.z = f2bf(acc[mi][ni][2] + bv[ni]);
                pk.w = f2bf(acc[mi][ni][3] + bv[ni]);
                *(ushort4*)(Vsh + base) = pk;
            }
        }
    }
}

// ---------- GEMM 64x128 tile, fp32 out: final projection ----------
__global__ __launch_bounds__(256, 4)
void gemm64(const unsigned short* __restrict__ A,
            const unsigned short* __restrict__ W,
            const float* __restrict__ bias, float* __restrict__ out)
{
    __shared__ unsigned short As[4096];   // [64][64]  8KB
    __shared__ unsigned short Ws[8192];   // [128][64] 16KB

    const int t = threadIdx.x;
    const int lane = t & 63;
    const int g = lane >> 4;
    const int c = lane & 15;
    const int w = t >> 6;
    const int wm = (w >> 1) * 32;
    const int wn = (w & 1) * 64;
    const int m0 = blockIdx.y * 64;
    const int n0 = blockIdx.x * 128;

    const int srow = lane >> 3;
    const int scol = (lane & 7) * 8;

    const f32x4 zz = {0.f, 0.f, 0.f, 0.f};
    f32x4 acc[2][4];
#pragma unroll
    for (int mi = 0; mi < 2; ++mi)
#pragma unroll
        for (int ni = 0; ni < 4; ++ni) acc[mi][ni] = zz;

    for (int kt = 0; kt < 16; ++kt) {
        const int k0 = kt * 64;
        gl16(A + (size_t)(m0 + 16 * w + srow) * 1024 + k0 + scol,
             (unsigned short*)As + (2 * w) * 512);
        gl16(A + (size_t)(m0 + 16 * w + 8 + srow) * 1024 + k0 + scol,
             (unsigned short*)As + (2 * w + 1) * 512);
#pragma unroll
        for (int r = 0; r < 4; ++r)
            gl16(W + (size_t)(n0 + 32 * w + 8 * r + srow) * 1024 + k0 + scol,
                 (unsigned short*)Ws + (w * 4 + r) * 512);
        __syncthreads();
#pragma unroll
        for (int kk = 0; kk < 2; ++kk) {
            fragAB af[2], bfr[4];
#pragma unroll
            for (int mi = 0; mi < 2; ++mi)
                af[mi] = *(const fragAB*)((char*)As + (wm + mi * 16 + c) * 128 + kk * 64 + g * 16);
#pragma unroll
            for (int ni = 0; ni < 4; ++ni)
                bfr[ni] = *(const fragAB*)((char*)Ws + (wn + ni * 16 + c) * 128 + kk * 64 + g * 16);
#pragma unroll
            for (int mi = 0; mi < 2; ++mi)
#pragma unroll
                for (int ni = 0; ni < 4; ++ni)
                    acc[mi][ni] = MFMA16(af[mi], bfr[ni], acc[mi][ni]);
        }
        __syncthreads();
    }

#pragma unroll
    for (int ni = 0; ni < 4; ++ni) {
        const float bv = bias[n0 + wn + ni * 16 + c];
#pragma unroll
        for (int mi = 0; mi < 2; ++mi)
#pragma unroll
            for (int j = 0; j < 4; ++j) {
                const int grow = m0 + wm + mi * 16 + g * 4 + j;
                const int gcol = n0 + wn + ni * 16 + c;
                out[(size_t)grow * 1024 + gcol] = acc[mi][ni][j] + bv;
            }
    }
}

// ---------- fused sine attention v6: barrier-free, all-global frag loads ----------
// QBLK=256, 8 waves = 4 q-slices(64 rows) x 2 k-halves. Grid 256 (1 block/CU),
// XCD-chunked. Per wave per iter: 8 contiguous 1KB frag loads (K 4 + V 4),
// register double-buffered one iter ahead (counted vmcnt, never drained);
// 16 MFMA32 + 32 sin. NO __syncthreads in main loop — waves free-run.
// LDS only for the final cross-k-half reduce (2 barriers total).
__global__ __launch_bounds__(512, 2)
void attn_kernel(const unsigned short* __restrict__ Qg,
                 const unsigned short* __restrict__ Ksh,
                 const unsigned short* __restrict__ Vsh,
                 unsigned short* __restrict__ AO)
{
    __shared__ float red[16384];   // 64KB reduce scratch (end only)

    const int t = threadIdx.x;
    const int lane = t & 63;
    const int l31 = lane & 31;
    const int lh = lane >> 5;
    const int w = t >> 6;
    const int qh = w >> 1;     // q-slice owned (64 rows)
    const int kbl = w & 1;     // k-half owned (32 of 64)

    // XCD-chunked bijective swizzle (256 blocks, 32 per XCD -> 4 (b,h) pairs/XCD)
    const int bid = blockIdx.x;
    const int lb = (bid & 7) * 32 + (bid >> 3);
    const int qb = lb & 7;
    const int h = (lb >> 3) & 15;
    const int b = lb >> 7;
    const int qbase = qb * 256;

    const unsigned short* Kc = Ksh + (size_t)(b * 16 + h) * 131072;
    const unsigned short* Vc = Vsh + (size_t)(b * 16 + h) * 131072;

    // per-wave contiguous frag bases
    const unsigned short* Kw = Kc + (size_t)kbl * 2048 + lane * 8;       // + kb*4096 + ds*512
    const unsigned short* Vw = Vc + (size_t)kbl * 2048 + lane * 8;       // + kb*4096 + j*512

    // Q fragments (loop-invariant): qf[qi][ds], rows qbase+qh*64+qi*32+l31
    fragAB qf[2][4];
#pragma unroll
    for (int qi = 0; qi < 2; ++qi)
#pragma unroll
        for (int ds = 0; ds < 4; ++ds)
            qf[qi][ds] = *(const fragAB*)(Qg
                + (size_t)(b * 2048 + qbase + qh * 64 + qi * 32 + l31) * 1024
                + h * 64 + ds * 16 + lh * 8);

    f32x16 o[2][2];
#pragma unroll
    for (int qi = 0; qi < 2; ++qi)
#pragma unroll
        for (int ni = 0; ni < 2; ++ni)
#pragma unroll
            for (int r = 0; r < 16; ++r) o[qi][ni][r] = 0.f;

    // register double-buffer: A = current, B = next
    fragAB kfA[4], vfA[4], kfB[4], vfB[4];
#pragma unroll
    for (int ds = 0; ds < 4; ++ds) kfA[ds] = *(const fragAB*)(Kw + ds * 512);
#pragma unroll
    for (int j = 0; j < 4; ++j)    vfA[j]  = *(const fragAB*)(Vw + j * 512);

    auto body = [&](int kb, fragAB (&kfc)[4], fragAB (&vfc)[4],
                            fragAB (&kfn)[4], fragAB (&vfn)[4]) {
        if (kb < 31) {   // prefetch kb+1 into next regs (counted vmcnt, no drain)
            const size_t so = (size_t)(kb + 1) * 4096;
#pragma unroll
            for (int ds = 0; ds < 4; ++ds) kfn[ds] = *(const fragAB*)(Kw + so + ds * 512);
#pragma unroll
            for (int j = 0; j < 4; ++j)    vfn[j]  = *(const fragAB*)(Vw + so + j * 512);
        }

        // QK: st[qi] = K(own 32k) . Q(qi-th 32q)^T over d=64
        f32x16 st[2];
#pragma unroll
        for (int qi = 0; qi < 2; ++qi)
#pragma unroll
            for (int r = 0; r < 16; ++r) st[qi][r] = 0.f;
        __builtin_amdgcn_s_setprio(1);
#pragma unroll
        for (int qi = 0; qi < 2; ++qi)
#pragma unroll
            for (int ds = 0; ds < 4; ++ds)
                st[qi] = MFMA32(kfc[ds], qf[qi][ds], st[qi]);
        __builtin_amdgcn_s_setprio(0);

        // per qi: sin -> bf16 pairs -> permlane32_swap -> PV
#pragma unroll
        for (int qi = 0; qi < 2; ++qi) {
            unsigned int u[8];
#pragma unroll
            for (int i = 0; i < 8; ++i)
                u[i] = cvtpk(fsin_rev(st[qi][2 * i] * SIN_SC),
                             fsin_rev(st[qi][2 * i + 1] * SIN_SC));
            swap32(u[0], u[2]); swap32(u[1], u[3]);
            swap32(u[4], u[6]); swap32(u[5], u[7]);
            union { u32x4 u; fragAB f; } pa0, pa1;
            pa0.u = (u32x4){u[0], u[1], u[2], u[3]};
            pa1.u = (u32x4){u[4], u[5], u[6], u[7]};
            __builtin_amdgcn_s_setprio(1);
#pragma unroll
            for (int ni = 0; ni < 2; ++ni) {
                o[qi][ni] = MFMA32(pa0.f, vfc[ni], o[qi][ni]);
                o[qi][ni] = MFMA32(pa1.f, vfc[2 + ni], o[qi][ni]);
            }
            __builtin_amdgcn_s_setprio(0);
        }
    };

    for (int tt = 0; tt < 16; ++tt) {
        body(2 * tt,     kfA, vfA, kfB, vfB);
        body(2 * tt + 1, kfB, vfB, kfA, vfA);
    }

    // cross-k-half reduce: kbl=1 waves write partial O, kbl=0 waves add + store
    if (kbl) {
#pragma unroll
        for (int qi = 0; qi < 2; ++qi)
#pragma unroll
            for (int ni = 0; ni < 2; ++ni)
#pragma unroll
                for (int r = 0; r < 16; ++r)
                    red[(((qh * 2 + qi) * 2 + ni) * 16 + r) * 64 + lane] = o[qi][ni][r];
    }
    __syncthreads();
    if (!kbl) {
#pragma unroll
        for (int qi = 0; qi < 2; ++qi)
#pragma unroll
            for (int ni = 0; ni < 2; ++ni)
#pragma unroll
                for (int r = 0; r < 16; ++r) {
                    const float v = o[qi][ni][r]
                        + red[(((qh * 2 + qi) * 2 + ni) * 16 + r) * 64 + lane];
                    const int q = qbase + qh * 64 + qi * 32 + (r & 3) + 8 * (r >> 2) + 4 * lh;
                    AO[(size_t)(b * 2048 + q) * 1024 + h * 64 + ni * 32 + l31] = f2bf(v);
                }
    }
}

// ---------- launcher ----------
extern "C" void kernel_launch(void* const* d_in, const int* in_sizes, int n_in,
                              void* d_out, int out_size, void* d_ws, size_t ws_size,
                              hipStream_t stream) {
    (void)in_sizes; (void)n_in; (void)out_size; (void)ws_size;
    const float* x  = (const float*)d_in[0];
    const float* Wq = (const float*)d_in[1];
    const float* bq = (const float*)d_in[2];
    const float* Wk = (const float*)d_in[3];
    const float* bk = (const float*)d_in[4];
    const float* Wv = (const float*)d_in[5];
    const float* bv = (const float*)d_in[6];
    const float* Wo = (const float*)d_in[7];
    const float* bo = (const float*)d_in[8];

    char* ws = (char*)d_ws;
    unsigned short* xb    = (unsigned short*)(ws);                    // 8MB
    unsigned short* Wqb   = (unsigned short*)(ws + (8u  << 20));      // 2MB each
    unsigned short* Wkb   = (unsigned short*)(ws + (10u << 20));
    unsigned short* Wvb   = (unsigned short*)(ws + (12u << 20));
    unsigned short* Wob   = (unsigned short*)(ws + (14u << 20));
    unsigned short* Qb    = (unsigned short*)(ws + (16u << 20));      // 8MB row-major
    unsigned short* Kshuf = (unsigned short*)(ws + (24u << 20));      // 8MB frag-order
    unsigned short* Vshuf = (unsigned short*)(ws + (32u << 20));      // 8MB frag-order
    unsigned short* AO    = (unsigned short*)(ws + (40u << 20));      // 8MB row-major

    cvt_all<<<8192, 256, 0, stream>>>(x, Wq, Wk, Wv, Wo, xb, Wqb, Wkb, Wvb, Wob);

    gemm_k<<<dim3(8, 32, 3), 256, 0, stream>>>(xb, Wqb, Wkb, Wvb, bq, bk, bv,
                                               Qb, Kshuf, Vshuf);

    attn_kernel<<<256, 512, 0, stream>>>(Qb, Kshuf, Vshuf, AO);

    gemm64<<<dim3(8, 64), 256, 0, stream>>>(AO, Wob, bo, (float*)d_out);
}